// Round 2
// baseline (1979.290 us; speedup 1.0000x reference)
//
#include <hip/hip_runtime.h>
#include <math.h>

// FCM: mutual-kNN attention feature mixing. N=8192, D=256, K=16, fp32.
//   K1: sq[i] = ||f_i||^2
//   K2: fused fp32 GEMM (f f^T) + streaming per-row top-32 candidates (LDS state)
//   K2b: fp64 refine of the 32 candidates -> exact top-17 (d2, idx) + fp64 scores
//   K3: mutual check + sparse softmax (<=17 terms) + mix + normalize
#define NPTS 8192
#define DIM  256
#define NSLOT 17            // K+1 (includes self)
#define NCAND 32            // fp32 candidate pool per row
#define TM 32               // rows per block  -> grid = 256 blocks (1/CU)
#define TN 256              // cols per J-tile
#define KC 64               // k-chunk
#define BTHREADS 256

// ---------------- Kernel 1: row squared norms ----------------
__global__ void sq_kernel(const float* __restrict__ feats, float* __restrict__ sq) {
    int row  = blockIdx.x * 4 + (threadIdx.x >> 6);
    int lane = threadIdx.x & 63;
    const float4 v = *reinterpret_cast<const float4*>(feats + (size_t)row * DIM + lane * 4);
    float p = v.x * v.x + v.y * v.y + v.z * v.z + v.w * v.w;
#pragma unroll
    for (int off = 32; off > 0; off >>= 1) p += __shfl_down(p, off, 64);
    if (lane == 0) sq[row] = p;
}

// ---------------- Kernel 2: GEMM + fused top-32 candidate selection ----------------
// ty = tid>>5 (0..7) -> 4 rows each; tx = tid&31 -> 8 strided cols (tx + 32*cc).
// Wave w owns rows 8w..8w+7 -> topk state is wave-private.
__global__ __launch_bounds__(BTHREADS, 1) void gemm_topk_kernel(
    const float* __restrict__ feats, const float* __restrict__ sq,
    int* __restrict__ knn32) {
    __shared__ float AsF[KC * 36];       // [k][r ^ (k&28)]
    __shared__ float BsF[KC * TN];       // [k][c ^ (k&31)]
    __shared__ float sqs[TN];
    __shared__ float tk_key[TM][NCAND];
    __shared__ int   tk_idx[TM][NCAND];
    __shared__ float tk_thr[TM];         // current worst (max) key in pool
    __shared__ int   tk_wsl[TM];         // slot of the worst

    const int tid  = threadIdx.x;
    const int ty   = tid >> 5;
    const int tx   = tid & 31;
    const int row0 = blockIdx.x * TM;

    for (int s = tid; s < TM * NCAND; s += BTHREADS) {
        int r = s / NCAND, sl = s % NCAND;
        tk_key[r][sl] = INFINITY; tk_idx[r][sl] = -1;
    }
    if (tid < TM) { tk_thr[tid] = INFINITY; tk_wsl[tid] = 0; }

    for (int J = 0; J < NPTS; J += TN) {
        __syncthreads();               // prev epilogue done (also fences init)
        sqs[tid] = sq[J + tid];

        float acc[4][8];
#pragma unroll
        for (int rr = 0; rr < 4; ++rr)
#pragma unroll
            for (int cc = 0; cc < 8; ++cc) acc[rr][cc] = 0.f;

        for (int kc = 0; kc < DIM; kc += KC) {
            __syncthreads();
#pragma unroll
            for (int p = 0; p < (TM * KC / 4) / BTHREADS; ++p) {   // 2
                int s = tid + p * BTHREADS;
                int r = s >> 4, kq = s & 15;
                float4 v = *reinterpret_cast<const float4*>(
                    feats + (size_t)(row0 + r) * DIM + kc + kq * 4);
                int k0 = kq * 4;
                AsF[(k0 + 0) * 36 + (r ^ ((k0 + 0) & 28))] = v.x;
                AsF[(k0 + 1) * 36 + (r ^ ((k0 + 1) & 28))] = v.y;
                AsF[(k0 + 2) * 36 + (r ^ ((k0 + 2) & 28))] = v.z;
                AsF[(k0 + 3) * 36 + (r ^ ((k0 + 3) & 28))] = v.w;
            }
#pragma unroll
            for (int p = 0; p < (TN * KC / 4) / BTHREADS; ++p) {   // 16
                int s = tid + p * BTHREADS;
                int c = s >> 4, kq = s & 15;
                float4 v = *reinterpret_cast<const float4*>(
                    feats + (size_t)(J + c) * DIM + kc + kq * 4);
                int k0 = kq * 4;
                BsF[(k0 + 0) * TN + (c ^ ((k0 + 0) & 31))] = v.x;
                BsF[(k0 + 1) * TN + (c ^ ((k0 + 1) & 31))] = v.y;
                BsF[(k0 + 2) * TN + (c ^ ((k0 + 2) & 31))] = v.z;
                BsF[(k0 + 3) * TN + (c ^ ((k0 + 3) & 31))] = v.w;
            }
            __syncthreads();
#pragma unroll 16
            for (int k = 0; k < KC; ++k) {
                const float4 a = *reinterpret_cast<const float4*>(
                    &AsF[k * 36 + ((ty * 4) ^ (k & 28))]);
                const int bb = k * TN + (tx ^ (k & 31));
                float b[8];
#pragma unroll
                for (int cc = 0; cc < 8; ++cc) b[cc] = BsF[bb + 32 * cc];
                const float av[4] = {a.x, a.y, a.z, a.w};
#pragma unroll
                for (int rr = 0; rr < 4; ++rr)
#pragma unroll
                    for (int cc = 0; cc < 8; ++cc)
                        acc[rr][cc] = fmaf(av[rr], b[cc], acc[rr][cc]);
            }
        }
        // ---- candidate-pool epilogue (topk state is wave-private; no barrier)
        float key[4][8];
        bool anyf = false;
#pragma unroll
        for (int rr = 0; rr < 4; ++rr) {
            float th = tk_thr[ty * 4 + rr];
#pragma unroll
            for (int cc = 0; cc < 8; ++cc) {
                float kk = sqs[tx + 32 * cc] - 2.0f * acc[rr][cc];
                key[rr][cc] = kk;
                anyf |= (kk < th);
            }
        }
        unsigned long long bal = __ballot(anyf);
        if (bal) {
            unsigned m32 = (unsigned)(bal | (bal >> 32));  // fold halves -> per-tx mask
            while (m32) {
                int sbit = __builtin_ctz(m32);
                m32 &= m32 - 1;
                if (tx == sbit && anyf) {      // two lanes (ty pair): disjoint rows
#pragma unroll
                    for (int rr = 0; rr < 4; ++rr) {
                        int r = ty * 4 + rr;
#pragma unroll
                        for (int cc = 0; cc < 8; ++cc) {
                            float kk = key[rr][cc];
                            if (kk < tk_thr[r]) {
                                int w = tk_wsl[r];
                                tk_key[r][w] = kk;
                                tk_idx[r][w] = J + tx + 32 * cc;
                                float mx = tk_key[r][0]; int mi = 0;
#pragma unroll
                                for (int s2 = 1; s2 < NCAND; ++s2) {
                                    float kv = tk_key[r][s2];
                                    if (kv > mx) { mx = kv; mi = s2; }
                                }
                                tk_thr[r] = mx; tk_wsl[r] = mi;
                            }
                        }
                    }
                }
            }
        }
    }
    __syncthreads();
    for (int s = tid; s < TM * NCAND; s += BTHREADS) {
        int r = s / NCAND, sl = s % NCAND;
        knn32[(size_t)(row0 + r) * NCAND + sl] = tk_idx[r][sl];
    }
}

// ---------------- Kernel 2b: fp64 refine -> exact top-17 ----------------
// One wave per row; lane c=lane&31 owns candidate c (upper half mirrors lower).
__global__ void refine_kernel(const float* __restrict__ feats,
                              const int* __restrict__ knn32,
                              int* __restrict__ fidx, float* __restrict__ fscr) {
    __shared__ float fi_s[4][DIM];
    const int w = threadIdx.x >> 6, lane = threadIdx.x & 63;
    const int i = blockIdx.x * 4 + w;
    const float4 v = *reinterpret_cast<const float4*>(feats + (size_t)i * DIM + lane * 4);
    *reinterpret_cast<float4*>(&fi_s[w][lane * 4]) = v;
    __syncthreads();
    const int c = lane & 31;
    int j = knn32[(size_t)i * NCAND + c];
    const float* fj = feats + (size_t)j * DIM;
    double dot = 0.0, dd = 0.0;
    for (int dq = 0; dq < DIM / 4; ++dq) {
        float4 a = *reinterpret_cast<const float4*>(&fi_s[w][dq * 4]);
        float4 b = *reinterpret_cast<const float4*>(fj + dq * 4);
        double dx = (double)a.x - (double)b.x, dy = (double)a.y - (double)b.y;
        double dz = (double)a.z - (double)b.z, dw2 = (double)a.w - (double)b.w;
        dd  += dx * dx + dy * dy + dz * dz + dw2 * dw2;
        dot += (double)a.x * b.x + (double)a.y * b.y + (double)a.z * b.z + (double)a.w * b.w;
    }
    float scr = (float)dot;
    for (int r = 0; r < NSLOT; ++r) {
        double mdd = dd; int mj = j; float ms = scr;
#pragma unroll
        for (int off = 1; off <= 16; off <<= 1) {
            double odd = __shfl_xor(mdd, off, 64);
            int    oj  = __shfl_xor(mj, off, 64);
            float  os  = __shfl_xor(ms, off, 64);
            if (odd < mdd || (odd == mdd && oj < mj)) { mdd = odd; mj = oj; ms = os; }
        }
        if (lane == 0) {
            fidx[(size_t)i * NSLOT + r] = mj;
            fscr[(size_t)i * NSLOT + r] = ms;
        }
        if (j == mj) dd = 1e300;    // both mirror lanes retire it
    }
}

// ---------------- Kernel 3: mutual mask + sparse softmax + mix + normalize ----------------
__global__ void fcm_out_kernel(const float* __restrict__ feats,
                               const int* __restrict__ knn_idx,
                               const float* __restrict__ knn_scr,
                               float* __restrict__ out) {
    const int w    = threadIdx.x >> 6;
    const int lane = threadIdx.x & 63;
    const int i    = blockIdx.x * 4 + w;

    int jt = -1; float st = 0.f; bool valid = false;
    if (lane < NSLOT) {
        jt = knn_idx[(size_t)i * NSLOT + lane];
        st = knn_scr[(size_t)i * NSLOT + lane];
        if (jt != i) {  // exclude self; mutual: i must be in knn(jt)
            const int* nb = knn_idx + (size_t)jt * NSLOT;
#pragma unroll
            for (int s = 0; s < NSLOT; ++s) valid |= (nb[s] == i);
        }
    }
    float val = valid ? st : -INFINITY;
#pragma unroll
    for (int off = 32; off > 0; off >>= 1) val = fmaxf(val, __shfl_xor(val, off, 64));
    const float m  = fmaxf(1.0f, val);
    const float wt = valid ? expf(st - m) : 0.f;
    float ws = wt;
#pragma unroll
    for (int off = 32; off > 0; off >>= 1) ws += __shfl_xor(ws, off, 64);
    const float wdiag = expf(1.0f - m);
    const float inv   = 1.0f / (ws + wdiag);

    const float4 fi = *reinterpret_cast<const float4*>(feats + (size_t)i * DIM + lane * 4);
    float ax = fi.x * wdiag, ay = fi.y * wdiag, az = fi.z * wdiag, aw = fi.w * wdiag;
    for (int t = 0; t < NSLOT; ++t) {
        float wtt = __shfl(wt, t, 64);
        int   jj  = __shfl(jt, t, 64);
        if (wtt > 0.f) {
            const float4 fj = *reinterpret_cast<const float4*>(feats + (size_t)jj * DIM + lane * 4);
            ax = fmaf(wtt, fj.x, ax); ay = fmaf(wtt, fj.y, ay);
            az = fmaf(wtt, fj.z, az); aw = fmaf(wtt, fj.w, aw);
        }
    }
    const float ox = fmaf(ax, inv, fi.x), oy = fmaf(ay, inv, fi.y);
    const float oz = fmaf(az, inv, fi.z), ow = fmaf(aw, inv, fi.w);
    float nn = ox * ox + oy * oy + oz * oz + ow * ow;
#pragma unroll
    for (int off = 32; off > 0; off >>= 1) nn += __shfl_xor(nn, off, 64);
    const float scl = 1.0f / fmaxf(sqrtf(nn), 1e-12f);
    float4 o; o.x = ox * scl; o.y = oy * scl; o.z = oz * scl; o.w = ow * scl;
    *reinterpret_cast<float4*>(out + (size_t)i * DIM + lane * 4) = o;
}

extern "C" void kernel_launch(void* const* d_in, const int* in_sizes, int n_in,
                              void* d_out, int out_size, void* d_ws, size_t ws_size,
                              hipStream_t stream) {
    (void)in_sizes; (void)n_in; (void)out_size; (void)ws_size;
    const float* feats = (const float*)d_in[0];
    float* out = (float*)d_out;
    char* ws = (char*)d_ws;
    float* sq      = (float*)ws;                                    // 32 KB
    int*   knn32   = (int*)  (ws + 32768);                          // 8192*32*4 = 1 MB
    int*   fidx    = (int*)  (ws + 32768 + NPTS * NCAND * 4);       // 8192*17*4
    float* fscr    = (float*)(ws + 32768 + NPTS * NCAND * 4 + NPTS * NSLOT * 4);
    sq_kernel<<<NPTS / 4, 256, 0, stream>>>(feats, sq);
    gemm_topk_kernel<<<NPTS / TM, BTHREADS, 0, stream>>>(feats, sq, knn32);
    refine_kernel<<<NPTS / 4, 256, 0, stream>>>(feats, knn32, fidx, fscr);
    fcm_out_kernel<<<NPTS / 4, 256, 0, stream>>>(feats, fidx, fscr, out);
}

// Round 3
// 250.263 us; speedup vs baseline: 7.9088x; 7.9088x over previous
//
#include <hip/hip_runtime.h>
#include <math.h>

// FCM mutual-kNN attention mixing. N=8192, D=256, K=16.
//   K1 prep:   feats fp32 -> bf16 copy + row sqnorms
//   K2 gemm:   bf16 MFMA  G = F F^T  -> bf16 score panel (candidate precision only)
//   K3 select: per-row rank-40 threshold (binary-searched count) -> <=64 candidate idx
//   K4 refine: fp64 exact d2 + dot over candidates -> exact top-17 (d2, idx)
//   K5 out:    mutual mask + sparse softmax + mix + normalize
#define NPTS 8192
#define DIM  256
#define NSLOT 17
#define RSEL 40            // candidate rank target (margin over 17 covers bf16 error)
#define CAP  64            // candidate pool cap
typedef unsigned int uint;
typedef unsigned short ushort;
typedef __attribute__((ext_vector_type(8))) short bf16x8;
typedef __attribute__((ext_vector_type(4))) float f32x4;

__device__ __forceinline__ ushort f2bf(float f) {
    uint x = __float_as_uint(f);
    return (ushort)((x + 0x7fffu + ((x >> 16) & 1u)) >> 16);
}
__device__ __forceinline__ float bfu(uint u) { return __uint_as_float(u << 16); }

// ---------------- K1: bf16 copy + squared norms ----------------
__global__ void prep_kernel(const float* __restrict__ feats, ushort* __restrict__ fb,
                            float* __restrict__ sq) {
    const int row  = blockIdx.x * 4 + (threadIdx.x >> 6);
    const int lane = threadIdx.x & 63;
    const float4 v = *reinterpret_cast<const float4*>(feats + (size_t)row * DIM + lane * 4);
    ushort4 b; b.x = f2bf(v.x); b.y = f2bf(v.y); b.z = f2bf(v.z); b.w = f2bf(v.w);
    *reinterpret_cast<ushort4*>(fb + (size_t)row * DIM + lane * 4) = b;
    float p = v.x * v.x + v.y * v.y + v.z * v.z + v.w * v.w;
#pragma unroll
    for (int off = 32; off > 0; off >>= 1) p += __shfl_down(p, off, 64);
    if (lane == 0) sq[row] = p;
}

// ---------------- K2: bf16 MFMA GEMM -> bf16 scores panel ----------------
// 512 threads = 8 waves. Block owns 32 rows (A fully in regs), loops J tiles of 256 cols.
// B tile staged in LDS [col][k] (KCH=64..128) with byte^((col&7)<<4) swizzle.
__global__ __launch_bounds__(512, 1) void gemm_kernel(const ushort* __restrict__ fb,
                                                      ushort* __restrict__ scores,
                                                      int prow0) {
    __shared__ ushort Bs[256 * 128];     // 64 KB, swizzled [col][k]
    __shared__ ushort Cs[32][256];       // 16 KB repack buffer
    const int tid = threadIdx.x;
    const int w   = tid >> 6;
    const int l   = tid & 63;
    const int l15 = l & 15, lg = l >> 4;
    const int row0 = prow0 + blockIdx.x * 32;

    // A fragments: a[mf][ks] = F[row0+mf*16+(l&15)][ks*32 + lg*8 .. +7]
    bf16x8 a[2][8];
#pragma unroll
    for (int mf = 0; mf < 2; ++mf) {
        const ushort* ap = fb + (size_t)(row0 + mf * 16 + l15) * DIM + lg * 8;
#pragma unroll
        for (int ks = 0; ks < 8; ++ks)
            a[mf][ks] = *reinterpret_cast<const bf16x8*>(ap + ks * 32);
    }

    for (int J = 0; J < NPTS; J += 256) {
        f32x4 acc[2][2];
#pragma unroll
        for (int mf = 0; mf < 2; ++mf)
#pragma unroll
            for (int cf = 0; cf < 2; ++cf) acc[mf][cf] = (f32x4){0.f, 0.f, 0.f, 0.f};

#pragma unroll
        for (int chunk = 0; chunk < 2; ++chunk) {
            __syncthreads();                       // LDS free (prev compute/copyout done)
            const int kc = chunk * 128;
            // stage: each wave 8 iters x (1KB global load -> swizzled ds_write)
#pragma unroll
            for (int t = 0; t < 8; ++t) {
                const int q   = w * 8 + t;
                const int col = q * 4 + lg;        // 4 cols per iter per wave
                const bf16x8 v = *reinterpret_cast<const bf16x8*>(
                    fb + (size_t)(J + col) * DIM + kc + l15 * 8);
                const int dst = col * 256 + ((l15 * 16) ^ ((col & 7) << 4));
                *reinterpret_cast<bf16x8*>(reinterpret_cast<char*>(Bs) + dst) = v;
            }
            __syncthreads();
#pragma unroll
            for (int kk = 0; kk < 4; ++kk) {
                bf16x8 bfr[2];
#pragma unroll
                for (int cf = 0; cf < 2; ++cf) {
                    const int col = w * 32 + cf * 16 + l15;
                    const int kb  = (kk * 64 + lg * 16) ^ ((col & 7) << 4);
                    bfr[cf] = *reinterpret_cast<const bf16x8*>(
                        reinterpret_cast<const char*>(Bs) + col * 256 + kb);
                }
#pragma unroll
                for (int mf = 0; mf < 2; ++mf)
#pragma unroll
                    for (int cf = 0; cf < 2; ++cf)
                        acc[mf][cf] = __builtin_amdgcn_mfma_f32_16x16x32_bf16(
                            a[mf][chunk * 4 + kk], bfr[cf], acc[mf][cf], 0, 0, 0);
            }
        }
        // epilogue: C frags -> Cs (bf16) -> coalesced global store
#pragma unroll
        for (int mf = 0; mf < 2; ++mf)
#pragma unroll
            for (int cf = 0; cf < 2; ++cf)
#pragma unroll
                for (int r = 0; r < 4; ++r)
                    Cs[mf * 16 + lg * 4 + r][w * 32 + cf * 16 + l15] = f2bf(acc[mf][cf][r]);
        __syncthreads();
        {
            const int r  = tid >> 4;
            const int cb = (tid & 15) * 16;
            ushort* dst = scores + (size_t)(blockIdx.x * 32 + r) * NPTS + J + cb;
            *reinterpret_cast<uint4*>(dst)     = *reinterpret_cast<const uint4*>(&Cs[r][cb]);
            *reinterpret_cast<uint4*>(dst + 8) = *reinterpret_cast<const uint4*>(&Cs[r][cb + 8]);
        }
        // next iteration's first barrier protects Cs/Bs
    }
}

// ---------------- K3: per-row candidate selection (rank-RSEL threshold) ----------------
__global__ void select_kernel(const ushort* __restrict__ scores, const float* __restrict__ sq,
                              int* __restrict__ cand, int prow0) {
    __shared__ int wsum[4];
    __shared__ int scnt;
    __shared__ int cbuf[CAP];
    const int t = threadIdx.x, w = t >> 6, lane = t & 63;
    const int i = prow0 + blockIdx.x;
    const ushort* srow = scores + (size_t)blockIdx.x * NPTS;

    float key[32];
#pragma unroll
    for (int p = 0; p < 8; ++p) {
        const int j0 = p * 1024 + t * 4;
        const uint2  sv = *reinterpret_cast<const uint2*>(srow + j0);
        const float4 qv = *reinterpret_cast<const float4*>(sq + j0);
        key[p * 4 + 0] = qv.x - 2.f * bfu(sv.x & 0xffffu);
        key[p * 4 + 1] = qv.y - 2.f * bfu(sv.x >> 16);
        key[p * 4 + 2] = qv.z - 2.f * bfu(sv.y & 0xffffu);
        key[p * 4 + 3] = qv.w - 2.f * bfu(sv.y >> 16);
    }
    // binary search threshold T with RSEL <= count(key < T) <= CAP
    float lo = -4096.f, hi = 4096.f;
    for (int it = 0; it < 26; ++it) {
        const float mid = 0.5f * (lo + hi);
        int c = 0;
#pragma unroll
        for (int e = 0; e < 32; ++e) c += (key[e] < mid) ? 1 : 0;
#pragma unroll
        for (int off = 32; off > 0; off >>= 1) c += __shfl_down(c, off, 64);
        if (lane == 0) wsum[w] = c;
        __syncthreads();
        const int C = wsum[0] + wsum[1] + wsum[2] + wsum[3];
        __syncthreads();
        if (C < RSEL) lo = mid;
        else { hi = mid; if (C <= CAP) break; }
    }
    if (t == 0) scnt = 0;
    __syncthreads();
#pragma unroll
    for (int e = 0; e < 32; ++e) {
        if (key[e] < hi) {
            const int s = atomicAdd(&scnt, 1);
            if (s < CAP) cbuf[s] = (e >> 2) * 1024 + t * 4 + (e & 3);
        }
    }
    __syncthreads();
    const int n = min(scnt, CAP);
    if (t < CAP) cand[(size_t)i * CAP + t] = (t < n) ? cbuf[t] : -1;
}

// ---------------- K4: fp64 refine -> exact top-17 ----------------
__global__ void refine_kernel(const float* __restrict__ feats, const int* __restrict__ cand,
                              int* __restrict__ fidx, float* __restrict__ fscr) {
    __shared__ float fi_s[4][DIM];
    const int w = threadIdx.x >> 6, lane = threadIdx.x & 63;
    const int i = blockIdx.x * 4 + w;
    *reinterpret_cast<float4*>(&fi_s[w][lane * 4]) =
        *reinterpret_cast<const float4*>(feats + (size_t)i * DIM + lane * 4);
    __syncthreads();
    int j = cand[(size_t)i * CAP + lane];
    double dot = 0.0, dd = 1e300;
    if (j >= 0) {
        const float* fj = feats + (size_t)j * DIM;
        dd = 0.0;
        for (int dq = 0; dq < DIM / 4; ++dq) {
            float4 a4 = *reinterpret_cast<const float4*>(&fi_s[w][dq * 4]);
            float4 b4 = *reinterpret_cast<const float4*>(fj + dq * 4);
            double dx = (double)a4.x - b4.x, dy = (double)a4.y - b4.y;
            double dz = (double)a4.z - b4.z, dw2 = (double)a4.w - b4.w;
            dd  += dx * dx + dy * dy + dz * dz + dw2 * dw2;
            dot += (double)a4.x * b4.x + (double)a4.y * b4.y +
                   (double)a4.z * b4.z + (double)a4.w * b4.w;
        }
    } else j = 0x7fffffff;
    float scr = (float)dot;
    for (int r = 0; r < NSLOT; ++r) {
        double mdd = dd; int mj = j; float ms = scr;
#pragma unroll
        for (int off = 1; off <= 32; off <<= 1) {
            double odd = __shfl_xor(mdd, off, 64);
            int    oj  = __shfl_xor(mj, off, 64);
            float  os  = __shfl_xor(ms, off, 64);
            if (odd < mdd || (odd == mdd && oj < mj)) { mdd = odd; mj = oj; ms = os; }
        }
        if (lane == 0) {
            fidx[(size_t)i * NSLOT + r] = mj;
            fscr[(size_t)i * NSLOT + r] = ms;
        }
        if (j == mj) dd = 1e300;
    }
}

// ---------------- K5: mutual mask + sparse softmax + mix + normalize ----------------
__global__ void fcm_out_kernel(const float* __restrict__ feats,
                               const int* __restrict__ knn_idx,
                               const float* __restrict__ knn_scr,
                               float* __restrict__ out) {
    const int w    = threadIdx.x >> 6;
    const int lane = threadIdx.x & 63;
    const int i    = blockIdx.x * 4 + w;

    int jt = -1; float st = 0.f; bool valid = false;
    if (lane < NSLOT) {
        jt = knn_idx[(size_t)i * NSLOT + lane];
        st = knn_scr[(size_t)i * NSLOT + lane];
        if (jt != i) {
            const int* nb = knn_idx + (size_t)jt * NSLOT;
#pragma unroll
            for (int s = 0; s < NSLOT; ++s) valid |= (nb[s] == i);
        }
    }
    float val = valid ? st : -INFINITY;
#pragma unroll
    for (int off = 32; off > 0; off >>= 1) val = fmaxf(val, __shfl_xor(val, off, 64));
    const float m  = fmaxf(1.0f, val);
    const float wt = valid ? expf(st - m) : 0.f;
    float ws = wt;
#pragma unroll
    for (int off = 32; off > 0; off >>= 1) ws += __shfl_xor(ws, off, 64);
    const float wdiag = expf(1.0f - m);
    const float inv   = 1.0f / (ws + wdiag);

    const float4 fi = *reinterpret_cast<const float4*>(feats + (size_t)i * DIM + lane * 4);
    float ax = fi.x * wdiag, ay = fi.y * wdiag, az = fi.z * wdiag, aw = fi.w * wdiag;
    for (int t = 0; t < NSLOT; ++t) {
        float wtt = __shfl(wt, t, 64);
        int   jj  = __shfl(jt, t, 64);
        if (wtt > 0.f) {
            const float4 fj = *reinterpret_cast<const float4*>(feats + (size_t)jj * DIM + lane * 4);
            ax = fmaf(wtt, fj.x, ax); ay = fmaf(wtt, fj.y, ay);
            az = fmaf(wtt, fj.z, az); aw = fmaf(wtt, fj.w, aw);
        }
    }
    const float ox = fmaf(ax, inv, fi.x), oy = fmaf(ay, inv, fi.y);
    const float oz = fmaf(az, inv, fi.z), ow = fmaf(aw, inv, fi.w);
    float nn = ox * ox + oy * oy + oz * oz + ow * ow;
#pragma unroll
    for (int off = 32; off > 0; off >>= 1) nn += __shfl_xor(nn, off, 64);
    const float scl = 1.0f / fmaxf(sqrtf(nn), 1e-12f);
    float4 o; o.x = ox * scl; o.y = oy * scl; o.z = oz * scl; o.w = ow * scl;
    *reinterpret_cast<float4*>(out + (size_t)i * DIM + lane * 4) = o;
}

extern "C" void kernel_launch(void* const* d_in, const int* in_sizes, int n_in,
                              void* d_out, int out_size, void* d_ws, size_t ws_size,
                              hipStream_t stream) {
    (void)in_sizes; (void)n_in; (void)out_size;
    const float* feats = (const float*)d_in[0];
    float* out = (float*)d_out;
    char* ws = (char*)d_ws;
    // workspace layout
    float*  sq    = (float*) (ws);                               // 32 KB
    ushort* fb    = (ushort*)(ws + 32768);                       // 4 MB
    int*    cand  = (int*)   (ws + 32768 + 4194304);             // 2 MB
    int*    fidx  = (int*)   (ws + 32768 + 4194304 + 2097152);   // 544 KB
    float*  fscr  = (float*) (ws + 32768 + 4194304 + 2097152 + 557056);
    ushort* scores= (ushort*)(ws + 32768 + 4194304 + 2097152 + 2 * 557056);
    const size_t fixed = 32768 + 4194304 + 2097152 + 2 * 557056;

    int pr = NPTS;   // score-panel rows; shrink to fit ws
    while (pr > 32 && fixed + (size_t)pr * NPTS * 2 > ws_size) pr >>= 1;

    prep_kernel<<<NPTS / 4, 256, 0, stream>>>(feats, fb, sq);
    for (int p0 = 0; p0 < NPTS; p0 += pr) {
        gemm_kernel<<<pr / 32, 512, 0, stream>>>(fb, scores, p0);
        select_kernel<<<pr, 256, 0, stream>>>(scores, sq, cand, p0);
    }
    refine_kernel<<<NPTS / 4, 256, 0, stream>>>(feats, cand, fidx, fscr);
    fcm_out_kernel<<<NPTS / 4, 256, 0, stream>>>(feats, fidx, fscr, out);
}